// Round 2
// baseline (317.608 us; speedup 1.0000x reference)
//
#include <hip/hip_runtime.h>

// Problem dims (fixed by the reference)
#define B_ 32
#define T_ 168
#define M_ 1024
#define A_ 8
#define H_ 64
#define BT_ (B_ * T_)      // 5376
#define JT_ 8              // (b,t) rows per thread; BT_ % JT_ == 0

// ---------------------------------------------------------------------------
// Key insight (verified R1): the LSTM state (hn, cn) never feeds the output.
//   out[b,t,m] = dot(x, v_m) + mn*c1_m + mx*c2_m + c3_m
//   v_m[a] = sum_h assoc_w[m,a,h]*dense_w[m,h];  sb = sum_h assoc_b[m,h]*dense_w[m,h]
//   c1 = sum_h dense_w - sum_a v - sb ;  c2 = sb ;  c3 = dense_b[m]
// (the (mx-mn) normalization cancels against the inverse-norm)
//
// R2 restructure: table stored AoS-padded [M][12] so each thread grabs its
// coefficients as 3 float4s, then streams 8 (b,t) rows with fixed m ->
// coefficients amortized 8x, 16 float4 HBM loads in flight per thread.
// ---------------------------------------------------------------------------

__global__ __launch_bounds__(256) void precompute_kernel(
    const float* __restrict__ assoc_w,  // [M,A,H]
    const float* __restrict__ assoc_b,  // [M,H]
    const float* __restrict__ dense_w,  // [M,H,1]
    const float* __restrict__ dense_b,  // [M,1]
    float* __restrict__ table)          // [M][12]
{
    const int wave = threadIdx.x >> 6;           // 4 waves per block
    const int lane = threadIdx.x & 63;           // lane == h (H == 64)
    const int m    = blockIdx.x * 4 + wave;
    if (m >= M_) return;

    const float dw = dense_w[m * H_ + lane];
    const float ab = assoc_b[m * H_ + lane];

    float v[A_];
#pragma unroll
    for (int a = 0; a < A_; ++a)
        v[a] = assoc_w[(m * A_ + a) * H_ + lane] * dw;
    float sb = ab * dw;
    float sd = dw;

#pragma unroll
    for (int off = 32; off >= 1; off >>= 1) {
#pragma unroll
        for (int a = 0; a < A_; ++a) v[a] += __shfl_xor(v[a], off, 64);
        sb += __shfl_xor(sb, off, 64);
        sd += __shfl_xor(sd, off, 64);
    }

    if (lane == 0) {
        float sv = 0.f;
        float* t = table + m * 12;
#pragma unroll
        for (int a = 0; a < A_; ++a) { t[a] = v[a]; sv += v[a]; }
        t[8]  = sd - sv - sb;   // c1 (mn coefficient)
        t[9]  = sb;             // c2 (mx coefficient)
        t[10] = dense_b[m];     // c3
        t[11] = 0.f;            // pad for float4 access
    }
}

// Thread u: m = u & 1023 (consecutive lanes -> consecutive m -> coalesced),
// bt rows [g*JT_, g*JT_+JT_) with g = u >> 10. Total threads = M_*BT_/JT_.
__global__ __launch_bounds__(256) void main_kernel(
    const float* __restrict__ x,      // [B,T,M,A]
    const float* __restrict__ table,  // [M][12]
    float* __restrict__ out)          // [B,T,M]
{
    const int u = blockIdx.x * 256 + threadIdx.x;
    const int m  = u & (M_ - 1);
    const int g  = u >> 10;
    if (g >= BT_ / JT_) return;
    const int bt0 = g * JT_;

    const float4* tp = (const float4*)(table + m * 12);
    const float4 t0 = tp[0];   // v0..v3
    const float4 t1 = tp[1];   // v4..v7
    const float4 t2 = tp[2];   // c1, c2, c3, pad

    // Load all 8 rows' x first (compiler hoists -> 16 outstanding float4 loads)
    float4 xa[JT_], xb[JT_];
#pragma unroll
    for (int j = 0; j < JT_; ++j) {
        const float4* xp =
            (const float4*)(x + ((size_t)(bt0 + j) * M_ + m) * A_);
        xa[j] = xp[0];
        xb[j] = xp[1];
    }

#pragma unroll
    for (int j = 0; j < JT_; ++j) {
        const float4 x0 = xa[j];
        const float4 x1 = xb[j];
        const float mn = fminf(fminf(fminf(x0.x, x0.y), fminf(x0.z, x0.w)),
                               fminf(fminf(x1.x, x1.y), fminf(x1.z, x1.w)));
        const float mx = fmaxf(fmaxf(fmaxf(x0.x, x0.y), fmaxf(x0.z, x0.w)),
                               fmaxf(fmaxf(x1.x, x1.y), fmaxf(x1.z, x1.w)));
        float dot;
        dot  = x0.x * t0.x;
        dot += x0.y * t0.y;
        dot += x0.z * t0.z;
        dot += x0.w * t0.w;
        dot += x1.x * t1.x;
        dot += x1.y * t1.y;
        dot += x1.z * t1.z;
        dot += x1.w * t1.w;
        out[(size_t)(bt0 + j) * M_ + m] = dot + mn * t2.x + mx * t2.y + t2.z;
    }
}

// Fallback if ws too small (48 KB needed): per-thread recompute, correct but slow.
__global__ __launch_bounds__(256) void fused_fallback_kernel(
    const float* __restrict__ x,
    const float* __restrict__ assoc_w,
    const float* __restrict__ assoc_b,
    const float* __restrict__ dense_w,
    const float* __restrict__ dense_b,
    float* __restrict__ out,
    int n)
{
    const int idx = blockIdx.x * 256 + threadIdx.x;
    if (idx >= n) return;
    const int m = idx & (M_ - 1);

    float v[A_] = {0.f};
    float sb = 0.f, sd = 0.f;
    for (int h = 0; h < H_; ++h) {
        const float dw = dense_w[m * H_ + h];
        sd += dw;
        sb += assoc_b[m * H_ + h] * dw;
#pragma unroll
        for (int a = 0; a < A_; ++a)
            v[a] += assoc_w[(m * A_ + a) * H_ + h] * dw;
    }
    float sv = 0.f;
#pragma unroll
    for (int a = 0; a < A_; ++a) sv += v[a];

    const float4* xp = (const float4*)(x + (size_t)idx * A_);
    const float4 x0 = xp[0];
    const float4 x1 = xp[1];
    const float xs[A_] = {x0.x, x0.y, x0.z, x0.w, x1.x, x1.y, x1.z, x1.w};

    float mn = xs[0], mx = xs[0], dot = 0.f;
#pragma unroll
    for (int a = 0; a < A_; ++a) {
        mn = fminf(mn, xs[a]);
        mx = fmaxf(mx, xs[a]);
        dot += xs[a] * v[a];
    }
    out[idx] = dot + mn * (sd - sv - sb) + mx * sb + dense_b[m];
}

extern "C" void kernel_launch(void* const* d_in, const int* in_sizes, int n_in,
                              void* d_out, int out_size, void* d_ws, size_t ws_size,
                              hipStream_t stream)
{
    const float* input   = (const float*)d_in[0];
    const float* assoc_w = (const float*)d_in[1];
    const float* assoc_b = (const float*)d_in[2];
    // d_in[3..6] = w_ih, w_hh, b_ih, b_hh -> dead w.r.t. the output
    const float* dense_w = (const float*)d_in[7];
    const float* dense_b = (const float*)d_in[8];
    float* out = (float*)d_out;

    const int n = out_size;  // B*T*M = 5,505,024
    const size_t need = (size_t)M_ * 12 * sizeof(float);

    if (ws_size >= need) {
        float* table = (float*)d_ws;
        precompute_kernel<<<M_ / 4, 256, 0, stream>>>(assoc_w, assoc_b,
                                                      dense_w, dense_b, table);
        const int total = M_ * (BT_ / JT_);          // 688,128 threads
        main_kernel<<<(total + 255) / 256, 256, 0, stream>>>(input, table, out);
    } else {
        fused_fallback_kernel<<<(n + 255) / 256, 256, 0, stream>>>(
            input, assoc_w, assoc_b, dense_w, dense_b, out, n);
    }
}